// Round 1
// baseline (974.797 us; speedup 1.0000x reference)
//
#include <hip/hip_runtime.h>

// Terrain3D: splat N gaussians into H(G^3) + E(4,G^3), one leak+laplacian+relu
// step, then trilinear-sample 8192 points x 5 channels.
//
// ws layout: [0 .. G3)        = H grid
//            [c*G3 .. (c+1)G3) = E channel c-1, c = 1..4

namespace {
constexpr int   G      = 128;
constexpr int   G3     = G * G * G;
constexpr int   NE     = 4;
constexpr int   RAD    = 9;            // max(2, int(3*0.05*128/2)) = 9
constexpr int   W      = 2 * RAD + 1;  // 19
constexpr float SIG    = 0.05f * (float)G * 0.5f;  // 3.2
constexpr float INV2S2 = 1.0f / (2.0f * SIG * SIG);
constexpr float ETA    = 0.01f;
constexpr float A_H    = 0.002f;
constexpr float A_E    = 0.001f;
constexpr float LEAK   = 5e-5f;
}

// ---------------------------------------------------------------------------
// 1) ws[0:G3) = H0 ; ws[G3:5*G3) = E0   (float4 copy)
// ---------------------------------------------------------------------------
__global__ void init_ws(const float4* __restrict__ H0, const float4* __restrict__ E0,
                        float4* __restrict__ ws) {
    int i = blockIdx.x * blockDim.x + threadIdx.x;
    constexpr int nH4 = G3 / 4;
    constexpr int n4  = 5 * G3 / 4;
    if (i < nH4)      ws[i] = H0[i];
    else if (i < n4)  ws[i] = E0[i - nH4];
}

// ---------------------------------------------------------------------------
// 2) splat: one block (256 threads) per particle. Separable kernel weights
//    (omega folded into kx) live in LDS; inner loop = 2 muls + 5 atomics.
// ---------------------------------------------------------------------------
__global__ void __launch_bounds__(256) splat_kernel(const float* __restrict__ pos,
                                                    const float* __restrict__ inten,
                                                    const float* __restrict__ emo,
                                                    float* __restrict__ ws) {
    const int p   = blockIdx.x;
    const int tid = threadIdx.x;

    __shared__ float kx[W], ky[W], kz[W], em[NE];
    __shared__ int   cbase[3];

    if (tid < 3 * W) {
        const int axis = tid / W;
        const int off  = tid - axis * W;
        const float gp = (pos[p * 3 + axis] + 1.0f) * 0.5f * (float)(G - 1);
        int c = (int)floorf(gp);
        c = min(max(c, 0), G - 1);
        const int coord = c + off - RAD;
        float k = 0.0f;
        if (coord >= 0 && coord < G) {
            const float d = (float)coord - gp;
            k = __expf(-d * d * INV2S2);
        }
        if (axis == 0) {
            kx[off] = k * inten[p] * ETA;   // fold omega into kx
            if (off == 0) cbase[0] = c;
        } else if (axis == 1) {
            ky[off] = k;
            if (off == 0) cbase[1] = c;
        } else {
            kz[off] = k;
            if (off == 0) cbase[2] = c;
        }
    }
    if (tid < NE) em[tid] = emo[p * NE + tid];
    __syncthreads();

    const int cx = cbase[0], cy = cbase[1], cz = cbase[2];
    const float e0 = em[0], e1 = em[1], e2 = em[2], e3 = em[3];

    // voxel linear index: k fastest (maps to contiguous global addresses)
    for (int v = tid; v < W * W * W; v += 256) {
        const int k = v % W;
        const int r = v / W;
        const int j = r % W;
        const int i = r / W;
        const float wxy = kx[i] * ky[j];
        const float val = wxy * kz[k];
        if (val != 0.0f) {   // zero <=> some axis out of [0,G) (or omega==0)
            const int idx = ((cx + i - RAD) * G + (cy + j - RAD)) * G + (cz + k - RAD);
            atomicAdd(&ws[idx],          val);
            atomicAdd(&ws[G3     + idx], val * e0);
            atomicAdd(&ws[2 * G3 + idx], val * e1);
            atomicAdd(&ws[3 * G3 + idx], val * e2);
            atomicAdd(&ws[4 * G3 + idx], val * e3);
        }
    }
}

// ---------------------------------------------------------------------------
// 3) fused step (leak + alpha*laplacian, relu) + trilinear sample.
//    One thread per output element (8192 points x 5 channels).
//    NOTE the reference's transpose: splat flattens (c0*G+c1)*G+c2 but
//    sampling reads vol[comp2][comp1][comp0].
// ---------------------------------------------------------------------------
__device__ __forceinline__ float stepped_at(const float* __restrict__ vol,
                                            int z, int y, int x,
                                            float addc, float alpha) {
    const int zm = max(z - 1, 0), zp = min(z + 1, G - 1);
    const int ym = max(y - 1, 0), yp = min(y + 1, G - 1);
    const int xm = max(x - 1, 0), xp = min(x + 1, G - 1);
    const int f  = (z * G + y) * G + x;
    const float cv  = vol[f];
    const float lap = vol[(zm * G + y) * G + x] + vol[(zp * G + y) * G + x]
                    + vol[(z * G + ym) * G + x] + vol[(z * G + yp) * G + x]
                    + vol[f - 1 + (x - xm) - 0]  // careful: xm clamp
                    + vol[(z * G + y) * G + xp]
                    - 6.0f * cv;
    // (the xm term above is rewritten below for clarity/correctness)
    const float lap2 = vol[(zm * G + y) * G + x] + vol[(zp * G + y) * G + x]
                     + vol[(z * G + ym) * G + x] + vol[(z * G + yp) * G + x]
                     + vol[(z * G + y) * G + xm] + vol[(z * G + y) * G + xp]
                     - 6.0f * cv;
    (void)lap;
    const float s = cv * (1.0f - LEAK) + addc + alpha * lap2;
    return fmaxf(s, 0.0f);
}

__global__ void __launch_bounds__(256) sample_kernel(const float* __restrict__ sp,
                                                     const float* __restrict__ ws,
                                                     float* __restrict__ out,
                                                     int n_out) {
    const int o = blockIdx.x * blockDim.x + threadIdx.x;
    if (o >= n_out) return;
    const int c = o % 5;       // 0 = H, 1..4 = E channels
    const int p = o / 5;

    const float t0 = fminf(fmaxf((sp[p * 3 + 0] + 1.0f) * 0.5f * (float)(G - 1), 0.0f), (float)(G - 1));
    const float t1 = fminf(fmaxf((sp[p * 3 + 1] + 1.0f) * 0.5f * (float)(G - 1), 0.0f), (float)(G - 1));
    const float t2 = fminf(fmaxf((sp[p * 3 + 2] + 1.0f) * 0.5f * (float)(G - 1), 0.0f), (float)(G - 1));

    const int a0 = (int)floorf(t0);  const float f0 = t0 - (float)a0;
    const int a1 = (int)floorf(t1);  const float f1 = t1 - (float)a1;
    const int a2 = (int)floorf(t2);  const float f2 = t2 - (float)a2;
    const int b0 = min(a0 + 1, G - 1);
    const int b1 = min(a1 + 1, G - 1);
    const int b2 = min(a2 + 1, G - 1);

    const float* vol  = ws + (size_t)c * G3;
    const float addc  = (c == 0) ? 0.0f : LEAK;
    const float alpha = (c == 0) ? A_H : A_E;

    float acc = 0.0f;
    // weight w2 pairs with comp2 which indexes the SLOWEST axis (ref transpose)
    for (int dz = 0; dz < 2; ++dz) {
        const int   z  = dz ? b2 : a2;
        const float w2 = dz ? f2 : 1.0f - f2;
        for (int dy = 0; dy < 2; ++dy) {
            const int   y  = dy ? b1 : a1;
            const float w1 = dy ? f1 : 1.0f - f1;
            for (int dx = 0; dx < 2; ++dx) {
                const int   x  = dx ? b0 : a0;
                const float w0 = dx ? f0 : 1.0f - f0;
                acc += (w2 * w1 * w0) * stepped_at(vol, z, y, x, addc, alpha);
            }
        }
    }
    out[o] = acc;
}

// ---------------------------------------------------------------------------
extern "C" void kernel_launch(void* const* d_in, const int* in_sizes, int n_in,
                              void* d_out, int out_size, void* d_ws, size_t ws_size,
                              hipStream_t stream) {
    const float* positions   = (const float*)d_in[0];  // (N,3)
    const float* intensities = (const float*)d_in[1];  // (N,)
    const float* emotions    = (const float*)d_in[2];  // (N,4)
    const float* sample_pos  = (const float*)d_in[3];  // (B,T,3)
    const float* H0          = (const float*)d_in[4];  // (G,G,G)
    const float* E0          = (const float*)d_in[5];  // (4,G,G,G)
    float* ws  = (float*)d_ws;
    float* out = (float*)d_out;

    const int N = in_sizes[0] / 3;

    constexpr int n4 = 5 * G3 / 4;
    init_ws<<<(n4 + 255) / 256, 256, 0, stream>>>(
        (const float4*)H0, (const float4*)E0, (float4*)ws);

    splat_kernel<<<N, 256, 0, stream>>>(positions, intensities, emotions, ws);

    sample_kernel<<<(out_size + 255) / 256, 256, 0, stream>>>(
        sample_pos, ws, out, out_size);
}

// Round 2
// 213.420 us; speedup vs baseline: 4.5675x; 4.5675x over previous
//
#include <hip/hip_runtime.h>

// Terrain3D — gather formulation.
// ws layout (floats): [0,5*G3) = H,E grids; then int counts[NTILES]; then
// int lists[NTILES*CAP].

namespace {
constexpr int   G      = 128;
constexpr int   G3     = G * G * G;
constexpr int   NE     = 4;
constexpr int   RAD    = 9;            // max(2, int(3*0.05*128/2)) = 9
constexpr float SIG    = 0.05f * (float)G * 0.5f;  // 3.2
constexpr float INV2S2 = 1.0f / (2.0f * SIG * SIG);
constexpr float ETA    = 0.01f;
constexpr float A_H    = 0.002f;
constexpr float A_E    = 0.001f;
constexpr float LEAK   = 5e-5f;

// tile geometry: 4 x 4 x 32 voxels (axis0 x axis1 x axis2; axis2 fastest in
// memory -> a wave stores two full 128-B rows)
constexpr int T0 = 4, T1 = 4, T2 = 32;
constexpr int NT0 = G / T0, NT1 = G / T1, NT2 = G / T2;   // 32, 32, 4
constexpr int NTILES = NT0 * NT1 * NT2;                   // 4096
constexpr int CAP = 128;   // mean particles/tile ~47, Poisson tail @128 ~0
}

__device__ __forceinline__ int clampi(int v, int lo, int hi) {
    return min(max(v, lo), hi);
}

// ---------------------------------------------------------------------------
// 1) bin: one thread per particle; append p to every tile its bbox overlaps.
// ---------------------------------------------------------------------------
__global__ void bin_kernel(const float* __restrict__ pos,
                           int* __restrict__ counts, int* __restrict__ lists,
                           int N) {
    const int p = blockIdx.x * blockDim.x + threadIdx.x;
    if (p >= N) return;
    int c[3];
#pragma unroll
    for (int a = 0; a < 3; ++a) {
        const float gp = (pos[p * 3 + a] + 1.0f) * 0.5f * (float)(G - 1);
        c[a] = clampi((int)floorf(gp), 0, G - 1);
    }
    const int l0 = max(c[0] - RAD, 0) / T0, h0 = min(c[0] + RAD, G - 1) / T0;
    const int l1 = max(c[1] - RAD, 0) / T1, h1 = min(c[1] + RAD, G - 1) / T1;
    const int l2 = max(c[2] - RAD, 0) / T2, h2 = min(c[2] + RAD, G - 1) / T2;
    for (int t0 = l0; t0 <= h0; ++t0)
        for (int t1 = l1; t1 <= h1; ++t1)
            for (int t2 = l2; t2 <= h2; ++t2) {
                const int t = (t0 * NT1 + t1) * NT2 + t2;
                const int slot = atomicAdd(&counts[t], 1);
                if (slot < CAP) lists[t * CAP + slot] = p;
            }
}

// ---------------------------------------------------------------------------
// 2) gather: one block per tile; each thread owns 2 voxels x 5 channels in
//    registers. No grid atomics; each voxel written exactly once. H0/E0 init
//    fused here.
// ---------------------------------------------------------------------------
__global__ void __launch_bounds__(256) gather_kernel(
        const float* __restrict__ pos, const float* __restrict__ inten,
        const float* __restrict__ emo,
        const float* __restrict__ H0, const float* __restrict__ E0,
        const int* __restrict__ counts, const int* __restrict__ lists,
        float* __restrict__ ws) {
    const int t  = blockIdx.x;
    const int t2 = t % NT2, t1 = (t / NT2) % NT1, t0 = t / (NT2 * NT1);
    const int tid = threadIdx.x;

    // voxel decomposition: axis2 fastest
    const int k = tid & (T2 - 1);          // 0..31
    const int j = (tid >> 5) & (T1 - 1);   // 0..3
    const int iA = tid >> 7;               // 0..1 ; second voxel: +2

    const int x2 = t2 * T2 + k;
    const int x1 = t1 * T1 + j;
    const int xA = t0 * T0 + iA;
    const int xB = xA + 2;

    const int flatA = (xA * G + x1) * G + x2;
    const int flatB = (xB * G + x1) * G + x2;

    float hA = H0[flatA], hB = H0[flatB];
    float eA[NE], eB[NE];
#pragma unroll
    for (int c = 0; c < NE; ++c) {
        eA[c] = E0[c * G3 + flatA];
        eB[c] = E0[c * G3 + flatB];
    }

    int cnt = counts[t];
    cnt = min(cnt, CAP);
    const int* __restrict__ lst = lists + t * CAP;

    const float fx1 = (float)x1, fx2 = (float)x2;
    const float fxA = (float)xA, fxB = (float)xB;

    int pn = (cnt > 0) ? lst[0] : 0;
    for (int n = 0; n < cnt; ++n) {
        const int p = pn;
        if (n + 1 < cnt) pn = lst[n + 1];   // software prefetch of next index

        const float gx = (pos[p * 3 + 0] + 1.0f) * 0.5f * (float)(G - 1);
        const float gy = (pos[p * 3 + 1] + 1.0f) * 0.5f * (float)(G - 1);
        const float gz = (pos[p * 3 + 2] + 1.0f) * 0.5f * (float)(G - 1);
        const int cx = clampi((int)floorf(gx), 0, G - 1);
        const int cy = clampi((int)floorf(gy), 0, G - 1);
        const int cz = clampi((int)floorf(gz), 0, G - 1);
        const float omega = inten[p] * ETA;
        const float m0 = emo[p * NE + 0], m1 = emo[p * NE + 1];
        const float m2 = emo[p * NE + 2], m3 = emo[p * NE + 3];

        // shared across the two voxels (they differ only in axis0)
        const float d1 = fx1 - gy, d2 = fx2 - gz;
        const float r12 = d1 * d1 + d2 * d2;
        const bool vYZ = (abs(x1 - cy) <= RAD) && (abs(x2 - cz) <= RAD);

        const float dA = fxA - gx, dB = fxB - gx;
        const bool vA = vYZ && (abs(xA - cx) <= RAD);
        const bool vB = vYZ && (abs(xB - cx) <= RAD);

        const float wA = vA ? __expf(-(dA * dA + r12) * INV2S2) * omega : 0.0f;
        const float wB = vB ? __expf(-(dB * dB + r12) * INV2S2) * omega : 0.0f;

        hA += wA;            hB += wB;
        eA[0] += wA * m0;    eB[0] += wB * m0;
        eA[1] += wA * m1;    eB[1] += wB * m1;
        eA[2] += wA * m2;    eB[2] += wB * m2;
        eA[3] += wA * m3;    eB[3] += wB * m3;
    }

    ws[flatA] = hA;  ws[flatB] = hB;
#pragma unroll
    for (int c = 0; c < NE; ++c) {
        ws[(c + 1) * G3 + flatA] = eA[c];
        ws[(c + 1) * G3 + flatB] = eB[c];
    }
}

// ---------------------------------------------------------------------------
// 3) fused step (leak + alpha*laplacian + relu) + trilinear sample.
//    8-way corner parallelism + shuffle reduction.
//    NOTE reference transpose: splat flattens (c0*G+c1)*G+c2 but sampling
//    reads vol[comp2][comp1][comp0] -> flat = comp2*G^2 + comp1*G + comp0.
// ---------------------------------------------------------------------------
__device__ __forceinline__ float stepped_at(const float* __restrict__ vol,
                                            int z, int y, int x,
                                            float addc, float alpha) {
    const int zm = max(z - 1, 0), zp = min(z + 1, G - 1);
    const int ym = max(y - 1, 0), yp = min(y + 1, G - 1);
    const int xm = max(x - 1, 0), xp = min(x + 1, G - 1);
    const float cv  = vol[(z * G + y) * G + x];
    const float lap = vol[(zm * G + y) * G + x] + vol[(zp * G + y) * G + x]
                    + vol[(z * G + ym) * G + x] + vol[(z * G + yp) * G + x]
                    + vol[(z * G + y) * G + xm] + vol[(z * G + y) * G + xp]
                    - 6.0f * cv;
    const float s = cv * (1.0f - LEAK) + addc + alpha * lap;
    return fmaxf(s, 0.0f);
}

__global__ void __launch_bounds__(256) sample_kernel(
        const float* __restrict__ sp, const float* __restrict__ ws,
        float* __restrict__ out, int n_out) {
    const int gt = blockIdx.x * blockDim.x + threadIdx.x;
    const int corner = gt & 7;
    const int o = gt >> 3;
    if (o >= n_out) return;
    const int c = o % 5;   // 0 = H, 1..4 = E
    const int p = o / 5;

    const float t0 = fminf(fmaxf((sp[p * 3 + 0] + 1.0f) * 0.5f * (float)(G - 1), 0.0f), (float)(G - 1));
    const float t1 = fminf(fmaxf((sp[p * 3 + 1] + 1.0f) * 0.5f * (float)(G - 1), 0.0f), (float)(G - 1));
    const float t2 = fminf(fmaxf((sp[p * 3 + 2] + 1.0f) * 0.5f * (float)(G - 1), 0.0f), (float)(G - 1));

    const int a0 = (int)floorf(t0);  const float f0 = t0 - (float)a0;
    const int a1 = (int)floorf(t1);  const float f1 = t1 - (float)a1;
    const int a2 = (int)floorf(t2);  const float f2 = t2 - (float)a2;
    const int b0 = min(a0 + 1, G - 1);
    const int b1 = min(a1 + 1, G - 1);
    const int b2 = min(a2 + 1, G - 1);

    const int d0 = corner & 1, d1 = (corner >> 1) & 1, d2 = corner >> 2;
    const int   x = d0 ? b0 : a0;          // comp0 -> fastest axis
    const int   y = d1 ? b1 : a1;          // comp1
    const int   z = d2 ? b2 : a2;          // comp2 -> slowest axis
    const float w = (d0 ? f0 : 1.0f - f0) * (d1 ? f1 : 1.0f - f1)
                  * (d2 ? f2 : 1.0f - f2);

    const float* vol  = ws + (size_t)c * G3;
    const float addc  = (c == 0) ? 0.0f : LEAK;
    const float alpha = (c == 0) ? A_H : A_E;

    float v = w * stepped_at(vol, z, y, x, addc, alpha);
    v += __shfl_xor(v, 1);
    v += __shfl_xor(v, 2);
    v += __shfl_xor(v, 4);
    if (corner == 0) out[o] = v;
}

// ---------------------------------------------------------------------------
extern "C" void kernel_launch(void* const* d_in, const int* in_sizes, int n_in,
                              void* d_out, int out_size, void* d_ws, size_t ws_size,
                              hipStream_t stream) {
    const float* positions   = (const float*)d_in[0];  // (N,3)
    const float* intensities = (const float*)d_in[1];  // (N,)
    const float* emotions    = (const float*)d_in[2];  // (N,4)
    const float* sample_pos  = (const float*)d_in[3];  // (B,T,3)
    const float* H0          = (const float*)d_in[4];  // (G,G,G)
    const float* E0          = (const float*)d_in[5];  // (4,G,G,G)
    float* ws  = (float*)d_ws;
    float* out = (float*)d_out;

    const int N = in_sizes[0] / 3;

    int* counts = (int*)(ws + 5 * (size_t)G3);
    int* lists  = counts + NTILES;

    hipMemsetAsync(counts, 0, NTILES * sizeof(int), stream);

    bin_kernel<<<(N + 255) / 256, 256, 0, stream>>>(positions, counts, lists, N);

    gather_kernel<<<NTILES, 256, 0, stream>>>(
        positions, intensities, emotions, H0, E0, counts, lists, ws);

    const int n_thr = out_size * 8;
    sample_kernel<<<(n_thr + 255) / 256, 256, 0, stream>>>(
        sample_pos, ws, out, out_size);
}

// Round 3
// 134.889 us; speedup vs baseline: 7.2266x; 1.5822x over previous
//
#include <hip/hip_runtime.h>

// Terrain3D — gather formulation with per-particle separable LDS tables.
// ws layout (floats): [0, 5*G3) = H,E grids; then int counts[NTILES];
// then int lists[NTILES*CAP]; then float4 meta[2*N] ({gx,gy,gz,omega},{m0..m3}).

namespace {
constexpr int   G      = 128;
constexpr int   G3     = G * G * G;
constexpr int   NE     = 4;
constexpr int   RAD    = 9;            // max(2, int(3*0.05*128/2)) = 9
constexpr float SIG    = 0.05f * (float)G * 0.5f;  // 3.2
constexpr float INV2S2 = 1.0f / (2.0f * SIG * SIG);
constexpr float ETA    = 0.01f;
constexpr float A_H    = 0.002f;
constexpr float A_E    = 0.001f;
constexpr float LEAK   = 5e-5f;

// tile geometry: 4 x 4 x 32 voxels (axis2 fastest in memory)
constexpr int T0 = 4, T1 = 4, T2 = 32;
constexpr int NT0 = G / T0, NT1 = G / T1, NT2 = G / T2;   // 32, 32, 4
constexpr int NTILES = NT0 * NT1 * NT2;                   // 4096
constexpr int CAP = 96;   // mean particles/tile ~47; Poisson tail @96 ~1e-10
}

__device__ __forceinline__ int clampi(int v, int lo, int hi) {
    return min(max(v, lo), hi);
}

// ---------------------------------------------------------------------------
// 1) bin + meta: one WAVE per particle. Lane 0 writes the particle meta;
//    lanes cover the <=6x6x2=72 candidate tiles of the bbox (1 atomic each).
// ---------------------------------------------------------------------------
__global__ void __launch_bounds__(256) bin_meta_kernel(
        const float* __restrict__ pos, const float* __restrict__ inten,
        const float4* __restrict__ emo4,
        int* __restrict__ counts, int* __restrict__ lists,
        float4* __restrict__ meta, int N) {
    const int p    = blockIdx.x * 4 + (threadIdx.x >> 6);
    const int lane = threadIdx.x & 63;
    if (p >= N) return;

    const float gx = (pos[p * 3 + 0] + 1.0f) * 0.5f * (float)(G - 1);
    const float gy = (pos[p * 3 + 1] + 1.0f) * 0.5f * (float)(G - 1);
    const float gz = (pos[p * 3 + 2] + 1.0f) * 0.5f * (float)(G - 1);
    const int c0 = clampi((int)floorf(gx), 0, G - 1);
    const int c1 = clampi((int)floorf(gy), 0, G - 1);
    const int c2 = clampi((int)floorf(gz), 0, G - 1);

    if (lane == 0) {
        meta[2 * p]     = make_float4(gx, gy, gz, inten[p] * ETA);
        meta[2 * p + 1] = emo4[p];
    }

    const int l0 = max(c0 - RAD, 0) >> 2, h0 = min(c0 + RAD, G - 1) >> 2;
    const int l1 = max(c1 - RAD, 0) >> 2, h1 = min(c1 + RAD, G - 1) >> 2;
    const int l2 = max(c2 - RAD, 0) >> 5, h2 = min(c2 + RAD, G - 1) >> 5;
    const int n0 = h0 - l0, n1 = h1 - l1, n2 = h2 - l2;  // inclusive spans - 1

    for (int s = lane; s < 72; s += 64) {          // fixed 6x6x2 slot grid
        const int a = s / 12;
        const int r = s - a * 12;
        const int b = r >> 1;
        const int cs = r & 1;
        if (a <= n0 && b <= n1 && cs <= n2) {
            const int t = ((l0 + a) * NT1 + (l1 + b)) * NT2 + (l2 + cs);
            const int slot = atomicAdd(&counts[t], 1);
            if (slot < CAP) lists[t * CAP + slot] = p;
        }
    }
}

// ---------------------------------------------------------------------------
// 2) gather: one block per tile. Build per-particle per-axis kernel tables
//    (validity zeros baked in, omega folded into kx) in LDS once, then the
//    inner loop is 3 LDS reads + 13 VALU per (thread, particle).
// ---------------------------------------------------------------------------
__global__ void __launch_bounds__(256) gather_kernel(
        const float4* __restrict__ meta,
        const float* __restrict__ H0, const float* __restrict__ E0,
        const int* __restrict__ counts, const int* __restrict__ lists,
        float* __restrict__ ws) {
    const int tile = blockIdx.x;
    const int t2 = tile % NT2, t1 = (tile / NT2) % NT1, t0 = tile / (NT2 * NT1);
    const int tid = threadIdx.x;

    __shared__ float kx[CAP * 4];
    __shared__ float ky[CAP * 4];
    __shared__ float kz[CAP * 32];

    const int cnt = min(counts[tile], CAP);
    const int* __restrict__ lst = lists + tile * CAP;

    // ---- build tables: 40 entries per particle (4 kx, 4 ky, 32 kz) ----
    const int b0 = t0 * T0, b1 = t1 * T1, b2 = t2 * T2;
    for (int t = tid; t < cnt * 40; t += 256) {
        const int n = t / 40;
        const int s = t - n * 40;
        const int p = lst[n];
        const int axis = (s < 4) ? 0 : (s < 8) ? 1 : 2;
        const int off  = (s < 4) ? s : (s < 8) ? s - 4 : s - 8;
        const float4 mg = meta[2 * p];
        const float g = (axis == 0) ? mg.x : (axis == 1) ? mg.y : mg.z;
        const int base = (axis == 0) ? b0 : (axis == 1) ? b1 : b2;
        const int cc = clampi((int)floorf(g), 0, G - 1);
        const int coord = base + off;
        const float d = (float)coord - g;
        float v = (abs(coord - cc) <= RAD) ? __expf(-d * d * INV2S2) : 0.0f;
        if (axis == 0) v *= mg.w;                 // fold omega into kx
        if (axis == 0)      kx[n * 4 + off] = v;
        else if (axis == 1) ky[n * 4 + off] = v;
        else                kz[n * 32 + off] = v;
    }
    __syncthreads();

    // ---- per-thread voxel ownership: axis2 fastest ----
    const int k  = tid & (T2 - 1);          // 0..31
    const int j  = (tid >> 5) & (T1 - 1);   // 0..3
    const int iA = tid >> 7;                // 0..1 ; second voxel: +2

    const int x2 = b2 + k, x1 = b1 + j, xA = b0 + iA, xB = xA + 2;
    const int flatA = (xA * G + x1) * G + x2;
    const int flatB = (xB * G + x1) * G + x2;

    float hA = H0[flatA], hB = H0[flatB];
    float eA[NE], eB[NE];
#pragma unroll
    for (int c = 0; c < NE; ++c) {
        eA[c] = E0[c * G3 + flatA];
        eB[c] = E0[c * G3 + flatB];
    }

    for (int n = 0; n < cnt; ++n) {
        const int p = lst[n];                     // uniform -> scalar load
        const float4 mm = meta[2 * p + 1];        // emotions, uniform
        const float kyz = ky[n * 4 + j] * kz[n * 32 + k];
        const float kxA = kx[n * 4 + iA];
        const float kxB = kx[n * 4 + iA + 2];
        const float wA = kxA * kyz;
        const float wB = kxB * kyz;
        hA += wA;            hB += wB;
        eA[0] += wA * mm.x;  eB[0] += wB * mm.x;
        eA[1] += wA * mm.y;  eB[1] += wB * mm.y;
        eA[2] += wA * mm.z;  eB[2] += wB * mm.z;
        eA[3] += wA * mm.w;  eB[3] += wB * mm.w;
    }

    ws[flatA] = hA;  ws[flatB] = hB;
#pragma unroll
    for (int c = 0; c < NE; ++c) {
        ws[(c + 1) * G3 + flatA] = eA[c];
        ws[(c + 1) * G3 + flatB] = eB[c];
    }
}

// ---------------------------------------------------------------------------
// 3) fused step (leak + alpha*laplacian + relu) + trilinear sample.
//    8-way corner parallelism + shuffle reduction.
//    NOTE reference transpose: splat flattens (c0*G+c1)*G+c2 but sampling
//    reads vol[comp2][comp1][comp0] -> flat = comp2*G^2 + comp1*G + comp0.
// ---------------------------------------------------------------------------
__device__ __forceinline__ float stepped_at(const float* __restrict__ vol,
                                            int z, int y, int x,
                                            float addc, float alpha) {
    const int zm = max(z - 1, 0), zp = min(z + 1, G - 1);
    const int ym = max(y - 1, 0), yp = min(y + 1, G - 1);
    const int xm = max(x - 1, 0), xp = min(x + 1, G - 1);
    const float cv  = vol[(z * G + y) * G + x];
    const float lap = vol[(zm * G + y) * G + x] + vol[(zp * G + y) * G + x]
                    + vol[(z * G + ym) * G + x] + vol[(z * G + yp) * G + x]
                    + vol[(z * G + y) * G + xm] + vol[(z * G + y) * G + xp]
                    - 6.0f * cv;
    const float s = cv * (1.0f - LEAK) + addc + alpha * lap;
    return fmaxf(s, 0.0f);
}

__global__ void __launch_bounds__(256) sample_kernel(
        const float* __restrict__ sp, const float* __restrict__ ws,
        float* __restrict__ out, int n_out) {
    const int gt = blockIdx.x * blockDim.x + threadIdx.x;
    const int corner = gt & 7;
    const int o = gt >> 3;
    if (o >= n_out) return;
    const int c = o % 5;   // 0 = H, 1..4 = E
    const int p = o / 5;

    const float t0 = fminf(fmaxf((sp[p * 3 + 0] + 1.0f) * 0.5f * (float)(G - 1), 0.0f), (float)(G - 1));
    const float t1 = fminf(fmaxf((sp[p * 3 + 1] + 1.0f) * 0.5f * (float)(G - 1), 0.0f), (float)(G - 1));
    const float t2 = fminf(fmaxf((sp[p * 3 + 2] + 1.0f) * 0.5f * (float)(G - 1), 0.0f), (float)(G - 1));

    const int a0 = (int)floorf(t0);  const float f0 = t0 - (float)a0;
    const int a1 = (int)floorf(t1);  const float f1 = t1 - (float)a1;
    const int a2 = (int)floorf(t2);  const float f2 = t2 - (float)a2;
    const int b0 = min(a0 + 1, G - 1);
    const int b1 = min(a1 + 1, G - 1);
    const int b2 = min(a2 + 1, G - 1);

    const int d0 = corner & 1, d1 = (corner >> 1) & 1, d2 = corner >> 2;
    const int   x = d0 ? b0 : a0;          // comp0 -> fastest axis
    const int   y = d1 ? b1 : a1;          // comp1
    const int   z = d2 ? b2 : a2;          // comp2 -> slowest axis
    const float w = (d0 ? f0 : 1.0f - f0) * (d1 ? f1 : 1.0f - f1)
                  * (d2 ? f2 : 1.0f - f2);

    const float* vol  = ws + (size_t)c * G3;
    const float addc  = (c == 0) ? 0.0f : LEAK;
    const float alpha = (c == 0) ? A_H : A_E;

    float v = w * stepped_at(vol, z, y, x, addc, alpha);
    v += __shfl_xor(v, 1);
    v += __shfl_xor(v, 2);
    v += __shfl_xor(v, 4);
    if (corner == 0) out[o] = v;
}

// ---------------------------------------------------------------------------
extern "C" void kernel_launch(void* const* d_in, const int* in_sizes, int n_in,
                              void* d_out, int out_size, void* d_ws, size_t ws_size,
                              hipStream_t stream) {
    const float* positions   = (const float*)d_in[0];  // (N,3)
    const float* intensities = (const float*)d_in[1];  // (N,)
    const float* emotions    = (const float*)d_in[2];  // (N,4)
    const float* sample_pos  = (const float*)d_in[3];  // (B,T,3)
    const float* H0          = (const float*)d_in[4];  // (G,G,G)
    const float* E0          = (const float*)d_in[5];  // (4,G,G,G)
    float* ws  = (float*)d_ws;
    float* out = (float*)d_out;

    const int N = in_sizes[0] / 3;

    int*    counts = (int*)(ws + 5 * (size_t)G3);
    int*    lists  = counts + NTILES;
    float4* meta   = (float4*)(lists + (size_t)NTILES * CAP);

    hipMemsetAsync(counts, 0, NTILES * sizeof(int), stream);

    bin_meta_kernel<<<(N + 3) / 4, 256, 0, stream>>>(
        positions, intensities, (const float4*)emotions, counts, lists, meta, N);

    gather_kernel<<<NTILES, 256, 0, stream>>>(
        meta, H0, E0, counts, lists, ws);

    const int n_thr = out_size * 8;
    sample_kernel<<<(n_thr + 255) / 256, 256, 0, stream>>>(
        sample_pos, ws, out, out_size);
}